// Round 12
// baseline (223.799 us; speedup 1.0000x reference)
//
#include <hip/hip_runtime.h>
#include <hip/hip_bf16.h>
#include <math.h>

// CausalMHA+RoPE: B=1, S=4096, DM=1024, H=16, DK=64. fp32 in / fp32 out.
// R23 = R22 design with the spill fixed. R22 post-mortem: __launch_bounds__
//      (512, 4) capped unified VGPR+AGPR at 128 and the accum_offset split
//      left 64 arch VGPRs -> spill (WRITE 8->33MB). The body needs ~80 arch
//      + 32 acc = 112 total, which ALREADY fits 4 waves/SIMD -- no hint
//      needed. Change: __launch_bounds__(512) (R18-proven: VGPR 80, clean).
//      Design (from R22): split each (head,pair) unit by q-half -> 512
//      blocks x 512 thr (8 waves = 2 ww x 4 kq), LDS 64 KB -> 2 barrier-
//      independent blocks/CU, both EXACTLY 33 steps; co-resident blocks
//      drift out of phase so one block's LDS flood overlaps the other's
//      MFMA/VALU. Both u-halves of a (head,jp) unit share an XCD (bid%8)
//      so duplicated K/V staging hits L2. Per-wave body verbatim R19.
//      Merge order (a0+a2)+(a1+a3) preserved -> bit-identical output.
//      prep/qkv/oproj unchanged.

#define SEQ 4096
#define DM  1024
#define NH  16
#define DK  64

typedef __attribute__((ext_vector_type(8))) short short8;    // 8 bf16 (MFMA A/B frag)
typedef __attribute__((ext_vector_type(4))) float floatx4;   // 16x16 C/D frag
typedef __attribute__((ext_vector_type(16))) float floatx16; // 32x32 C/D frag
typedef __attribute__((ext_vector_type(4))) short short4v;   // 4 bf16 (8 B)

static __device__ __forceinline__ short f2bf(float f) {
    __hip_bfloat16 h = __float2bfloat16(f);
    return __builtin_bit_cast(short, h);
}

static __device__ __forceinline__ float fast_exp2(float x) {
#if __has_builtin(__builtin_amdgcn_exp2f)
    return __builtin_amdgcn_exp2f(x);
#else
    return exp2f(x);
#endif
}

static __device__ __forceinline__ short8 load8_f32_as_bf16(const float* p) {
    float4 a = *reinterpret_cast<const float4*>(p);
    float4 b = *reinterpret_cast<const float4*>(p + 4);
    short8 s;
    s[0] = f2bf(a.x); s[1] = f2bf(a.y); s[2] = f2bf(a.z); s[3] = f2bf(a.w);
    s[4] = f2bf(b.x); s[5] = f2bf(b.y); s[6] = f2bf(b.z); s[7] = f2bf(b.w);
    return s;
}

// async global->LDS, 16 B/lane. LDS dest = wave-uniform base + lane*16.
static __device__ __forceinline__ void gl2lds16(const __hip_bfloat16* g, short* l) {
    __builtin_amdgcn_global_load_lds(
        (const __attribute__((address_space(1))) unsigned int*)g,
        (__attribute__((address_space(3))) unsigned int*)l, 16, 0, 0);
}

static __device__ __forceinline__ int read_pos(const int* tp32, int s) {
    return (tp32[1] == 1) ? tp32[s] : tp32[2 * s];
}

// ---------------------------------------------------------------------------
// Fused prep: fp32->bf16 for x/Wq/Wk/Wv + RoPE cos/sin table. Grid 4096.
// ---------------------------------------------------------------------------
__global__ __launch_bounds__(256) void prep_kernel(
    const float* __restrict__ x,  const float* __restrict__ Wq,
    const float* __restrict__ Wk, const float* __restrict__ Wv,
    const int* __restrict__ tp,
    __hip_bfloat16* __restrict__ xb,  __hip_bfloat16* __restrict__ Wqb,
    __hip_bfloat16* __restrict__ Wkb, __hip_bfloat16* __restrict__ Wvb,
    float2* __restrict__ tab)
{
    int b = blockIdx.x;
    if (b < 3584) {
        const float* src; __hip_bfloat16* dst; int off;
        if (b < 2048)      { src = x;  dst = xb;  off = b; }
        else if (b < 2560) { src = Wq; dst = Wqb; off = b - 2048; }
        else if (b < 3072) { src = Wk; dst = Wkb; off = b - 2560; }
        else               { src = Wv; dst = Wvb; off = b - 3072; }
        size_t i = (size_t)off * 256 + threadIdx.x;
        short8 v = load8_f32_as_bf16(src + i * 8);
        *reinterpret_cast<short8*>((short*)dst + i * 8) = v;
    } else {
        int idx = (b - 3584) * 256 + threadIdx.x;   // SEQ*32 entries
        if (idx < SEQ * 32) {
            int s = idx >> 5, pair = idx & 31;
            float inv_freq = exp2f(-(float)(2 * pair) * (13.287712379549449f / 64.f));
            float sn, cs;
            sincosf((float)read_pos(tp, s) * inv_freq, &sn, &cs);
            tab[idx] = make_float2(cs, sn);
        }
    }
}

// ---------------------------------------------------------------------------
// Kernel 1: QKV NT-GEMM + RoPE epilogue. qscale folds log2(e) so attn uses
// native exp2 (v_exp_f32) directly.
// ---------------------------------------------------------------------------
__global__ __launch_bounds__(256) void qkv_rope_kernel(
    const __hip_bfloat16* __restrict__ xb,
    const float2* __restrict__ tab,
    const __hip_bfloat16* __restrict__ Wqb,
    const __hip_bfloat16* __restrict__ Wkb,
    const __hip_bfloat16* __restrict__ Wvb,
    __hip_bfloat16* __restrict__ q_ws,
    __hip_bfloat16* __restrict__ k_ws,
    __hip_bfloat16* __restrict__ vt_ws)
{
    __shared__ __align__(16) short pool[17408];
    short* As = pool;
    short* Bs = pool + 8192;

    const int by = blockIdx.y;
    const int wsel = by >> 3;
    const __hip_bfloat16* W = (wsel == 0) ? Wqb : (wsel == 1 ? Wkb : Wvb);
    const int nloc0 = (by & 7) * 128;
    const int m0 = blockIdx.x * 128;

    const int t = threadIdx.x;
    const int lane = t & 63;
    const int w = t >> 6;
    const int quad = lane >> 4;
    const int ln = lane & 15;
    const int wm = (w >> 1) * 64;
    const int wn = (w & 1) * 64;

    floatx4 acc[4][4];
    #pragma unroll
    for (int i = 0; i < 4; i++)
        #pragma unroll
        for (int j = 0; j < 4; j++) acc[i][j] = (floatx4){0.f, 0.f, 0.f, 0.f};

    for (int k0 = 0; k0 < DM; k0 += 64) {
        #pragma unroll
        for (int it = 0; it < 4; it++) {
            int row = w * 32 + it * 8 + (lane >> 3);
            int sg = (lane & 7) ^ (row & 7);
            gl2lds16(&xb[(size_t)(m0 + row) * DM + k0 + sg * 8], &As[(w * 32 + it * 8) * 64]);
            gl2lds16(&W[(size_t)(nloc0 + row) * DM + k0 + sg * 8], &Bs[(w * 32 + it * 8) * 64]);
        }
        __syncthreads();

        short8 af[4][2], bfr[4][2];
        #pragma unroll
        for (int i = 0; i < 4; i++)
            #pragma unroll
            for (int kc = 0; kc < 2; kc++)
                af[i][kc] = *reinterpret_cast<const short8*>(
                    &As[(wm + i * 16 + ln) * 64 + (((kc * 4 + quad) ^ (ln & 7)) << 3)]);
        #pragma unroll
        for (int j = 0; j < 4; j++)
            #pragma unroll
            for (int kc = 0; kc < 2; kc++)
                bfr[j][kc] = *reinterpret_cast<const short8*>(
                    &Bs[(wn + j * 16 + ln) * 64 + (((kc * 4 + quad) ^ (ln & 7)) << 3)]);

        #pragma unroll
        for (int kc = 0; kc < 2; kc++)
            #pragma unroll
            for (int i = 0; i < 4; i++)
                #pragma unroll
                for (int j = 0; j < 4; j++)
                    acc[i][j] = __builtin_amdgcn_mfma_f32_16x16x32_bf16(
                        af[i][kc], bfr[j][kc], acc[i][j], 0, 0, 0);
        __syncthreads();
    }

    if (wsel < 2) {
        __hip_bfloat16* dst = (wsel == 0) ? q_ws : k_ws;
        // q scale = (1/sqrt(dk)) * log2(e) so attn softmax uses exp2 natively.
        const float qscale = (wsel == 0) ? 0.18033688011112042f : 1.0f;
        #pragma unroll
        for (int j = 0; j < 4; j++) {
            int cnl = wn + j * 16 + ln;
            int pair = ((nloc0 + cnl) & 63) >> 1;
            #pragma unroll
            for (int i = 0; i < 4; i++) {
                int rowl = wm + i * 16 + quad * 4;
                #pragma unroll
                for (int r = 0; r < 4; r++) {
                    float2 t2 = tab[(size_t)(m0 + rowl + r) * 32 + pair];
                    float val = acc[i][j][r];
                    float partner = __shfl_xor(val, 1, 64);
                    float res = val * t2.x + (((lane & 1) ? partner : -partner) * t2.y);
                    pool[(rowl + r) * 136 + cnl] = f2bf(res * qscale);
                }
            }
        }
        __syncthreads();
        int row = t >> 1, half = t & 1;
        size_t gbase = (size_t)(m0 + row) * DM + nloc0 + half * 64;
        #pragma unroll
        for (int c = 0; c < 8; c++)
            *reinterpret_cast<short8*>(&dst[gbase + c * 8]) =
                *reinterpret_cast<const short8*>(&pool[row * 136 + half * 64 + c * 8]);
    } else {
        #pragma unroll
        for (int j = 0; j < 4; j++) {
            int cnl = wn + j * 16 + ln;
            #pragma unroll
            for (int i = 0; i < 4; i++) {
                int s0 = wm + i * 16 + quad * 4;
                #pragma unroll
                for (int r = 0; r < 4; r++)
                    pool[cnl * 136 + s0 + r] = f2bf(acc[i][j][r]);
            }
        }
        __syncthreads();
        int cnl = t >> 1, sh = t & 1;
        size_t base = (size_t)(nloc0 + cnl) * SEQ + m0 + sh * 64;
        #pragma unroll
        for (int c = 0; c < 8; c++)
            *reinterpret_cast<short8*>(&vt_ws[base + c * 8]) =
                *reinterpret_cast<const short8*>(&pool[cnl * 136 + sh * 64 + c * 8]);
    }
}

// ---------------------------------------------------------------------------
// Kernel 2: causal flash attention, 32x32 MFMA, in-register softmax (R15
// math, verified; R19 body). R23: 512 blocks x 512 thr = 8 waves =
// 2 q-groups (ww) x 4 key quarters (kq); block handles the u-th 64-row
// half of both tiles of pair jp (A=31-jp then B=jp, uniform 33 steps).
// LDS 64 KB -> 2 barrier-independent blocks/CU (phase overlap).
// __launch_bounds__(512) ONLY -- no min-waves floor (R22's (512,4) capped
// arch VGPRs at 64 and spilled).
//
// Layouts (32x32x16 bf16):
//   A-frag: row = lane&31, k = (lane>>5)*8 + e
//   B-frag: col = lane&31, k = (lane>>5)*8 + e
//   C/D   : col = lane&31, row = (reg&3) + 8*(reg>>2) + 4*(lane>>5)
// K LDS rows permuted by swap(bit2,bit3) so S^T output regs are already in
// PV B-frag key order.
// ---------------------------------------------------------------------------
__global__ __launch_bounds__(512) void attn_kernel(
    const __hip_bfloat16* __restrict__ q_ws,
    const __hip_bfloat16* __restrict__ k_ws,
    const __hip_bfloat16* __restrict__ vt_ws,
    __hip_bfloat16* __restrict__ o_ws)   // [SEQ][DM]
{
    __shared__ __align__(16) short Kt[2][128 * 64];   // [buf][key_row][dk]  32 KB
    __shared__ __align__(16) short Vt[2][64 * 128];   // [buf][d][key]       32 KB

    const int bid = (int)blockIdx.x;
    const int head = bid & 15;            // 2 heads per XCD (bid%8 = XCD)
    const int rest = bid >> 4;            // 0..31
    const int jp = rest & 15;             // pair index
    const int u  = rest >> 4;             // q-half of the 128-row tile

    const int t = threadIdx.x;
    const int lane = t & 63;
    const int w = t >> 6;                 // 0..7
    const int ww = w & 1;                 // q-row group within 64-row half
    const int kq = w >> 1;                // key quarter = kb32
    const int hi = lane >> 5;             // k-half select
    const int l31 = lane & 31;

    auto stage = [&](int b, int kb) {     // stage keys [kb, kb+128), 8 waves
        #pragma unroll
        for (int i = 0; i < 2; i++) {     // K: 8 rows per issue x 2
            int r = w * 16 + i * 8 + (lane >> 3);
            int keyloc = (r & ~12) | ((r & 4) << 1) | ((r & 8) >> 1);  // swap b2<->b3
            int g = (lane & 7) ^ (r & 7);
            gl2lds16(&k_ws[(size_t)(kb + keyloc) * DM + head * 64 + g * 8],
                     &Kt[b][(w * 16 + i * 8) * 64]);
        }
        #pragma unroll
        for (int i = 0; i < 2; i++) {     // V^T: 4 d-rows per issue x 2
            int d = w * 8 + i * 4 + (lane >> 4);
            int g = (lane & 15) ^ (d & 7);
            gl2lds16(&vt_ws[(size_t)(head * 64 + d) * SEQ + kb + g * 8],
                     &Vt[b][(w * 8 + i * 4) * 128]);
        }
    };

    #pragma unroll 1
    for (int pass = 0; pass < 2; pass++) {
        const int tile = pass ? jp : (31 - jp);
        const int nstep = tile + 1;                    // 128-key steps
        const int q0 = tile * 128 + u * 64 + ww * 32;  // wave's first q row
        const int qoff = u * 64 + ww * 32;             // within-tile q offset

        // Q fragments (B operand), k-chunk c: k = c*16 + hi*8 + 0..7
        short8 qf[4];
        #pragma unroll
        for (int c = 0; c < 4; c++)
            qf[c] = *reinterpret_cast<const short8*>(
                &q_ws[(size_t)(q0 + l31) * DM + head * 64 + c * 16 + hi * 8]);

        floatx16 accO[2];
        #pragma unroll
        for (int db = 0; db < 2; db++)
            #pragma unroll
            for (int i = 0; i < 16; i++) accO[db][i] = 0.f;
        float l = 0.f;

        __syncthreads();                  // prior pass LDS reads done
        stage(0, 0);
        int buf = 0;
        for (int st = 0; st < nstep; st++) {
            __syncthreads();
            if (st + 1 < nstep) stage(buf ^ 1, (st + 1) * 128);
            const bool last = (st == nstep - 1);

            if (!(last && kq > (qoff >> 5))) {    // wave-uniform skip above diagonal
                const int krow = kq * 32 + l31;   // Kt physical row
                short8 kfr[4];
                #pragma unroll
                for (int kc = 0; kc < 4; kc++) {
                    int g = (kc * 2 + hi) ^ (krow & 7);
                    kfr[kc] = *reinterpret_cast<const short8*>(&Kt[buf][krow * 64 + g * 8]);
                }
                floatx16 s;
                #pragma unroll
                for (int i = 0; i < 16; i++) s[i] = 0.f;
                __builtin_amdgcn_s_setprio(1);
                #pragma unroll
                for (int kc = 0; kc < 4; kc++)
                    s = __builtin_amdgcn_mfma_f32_32x32x16_bf16(kfr[kc], qf[kc], s, 0, 0, 0);
                __builtin_amdgcn_s_setprio(0);

                if (last) {                       // diagonal mask (key = swapped row)
                    #pragma unroll
                    for (int r = 0; r < 16; r++) {
                        int key_l = kq * 32 + (r & 7) + 2 * (r & 8) + 8 * hi;
                        if (key_l > qoff + l31) s[r] = -1e9f;
                    }
                }
                float p[16];
                #pragma unroll
                for (int r = 0; r < 16; r++) { p[r] = fast_exp2(s[r]); l += p[r]; }

                // P B-frags in key-natural order: chunk c -> keys c*16+hi*8+e
                union { short8 v; short e[8]; } pb[2];
                #pragma unroll
                for (int c = 0; c < 2; c++)
                    #pragma unroll
                    for (int e8 = 0; e8 < 8; e8++)
                        pb[c].e[e8] = f2bf(p[c * 8 + e8]);

                #pragma unroll
                for (int db = 0; db < 2; db++) {
                    const int vrow = db * 32 + l31;
                    short8 vfr[2];
                    #pragma unroll
                    for (int c = 0; c < 2; c++) {
                        int g = (kq * 4 + c * 2 + hi) ^ (vrow & 7);
                        vfr[c] = *reinterpret_cast<const short8*>(&Vt[buf][vrow * 128 + g * 8]);
                    }
                    __builtin_amdgcn_s_setprio(1);
                    accO[db] = __builtin_amdgcn_mfma_f32_32x32x16_bf16(vfr[0], pb[0].v, accO[db], 0, 0, 0);
                    accO[db] = __builtin_amdgcn_mfma_f32_32x32x16_bf16(vfr[1], pb[1].v, accO[db], 0, 0, 0);
                    __builtin_amdgcn_s_setprio(0);
                }
            }
            buf ^= 1;
        }

        // ---- 4-way merge over key quarters (accO, l additive over keys) ----
        // Order (a0+a2)+(a1+a3) as R19. SoA scratch in Kt (f32 planes,
        // 4B lane stride = conflict-free); l values in Vt.
        float* scrK = (float*)Kt;
        float* scrV = (float*)Vt;
        __syncthreads();                  // all Kt/Vt compute reads done
        {   // Round 1a: kq{2,3} -> kq{0,1}: accO[0] + l
            const int slot = (ww * 2 + (kq & 1)) * 64 + lane;   // 0..255
            if (kq >= 2) {
                #pragma unroll
                for (int i = 0; i < 16; i++) scrK[i * 256 + slot] = accO[0][i];
                scrV[slot] = l;
            }
            __syncthreads();
            if (kq < 2) {
                #pragma unroll
                for (int i = 0; i < 16; i++) accO[0][i] += scrK[i * 256 + slot];
                l += scrV[slot];
            }
            __syncthreads();
            // Round 1b: accO[1]
            if (kq >= 2) {
                #pragma unroll
                for (int i = 0; i < 16; i++) scrK[i * 256 + slot] = accO[1][i];
            }
            __syncthreads();
            if (kq < 2) {
                #pragma unroll
                for (int i = 0; i < 16; i++) accO[1][i] += scrK[i * 256 + slot];
            }
            __syncthreads();
            // Round 2: kq1 -> kq0: accO[0..1] + l
            const int slot2 = ww * 64 + lane;   // 0..127
            if (kq == 1) {
                #pragma unroll
                for (int i = 0; i < 16; i++) scrK[i * 128 + slot2] = accO[0][i];
                #pragma unroll
                for (int i = 0; i < 16; i++) scrK[(16 + i) * 128 + slot2] = accO[1][i];
                scrV[slot2] = l;
            }
            __syncthreads();
            if (kq == 0) {
                #pragma unroll
                for (int i = 0; i < 16; i++) accO[0][i] += scrK[i * 128 + slot2];
                #pragma unroll
                for (int i = 0; i < 16; i++) accO[1][i] += scrK[(16 + i) * 128 + slot2];
                l += scrV[slot2];
            }
        }

        // Epilogue (kq=0 waves hold full sums): l fold, scale, pool, stores.
        float lf = l + __shfl_xor(l, 32, 64);
        float rl = 1.f / lf;

        __syncthreads();                  // round-2 scratch reads done
        short* pool = (short*)Kt;         // 64 x 68 bf16 = 8704 B
        if (kq == 0) {
            const int qrow = ww * 32 + l31;
            #pragma unroll
            for (int db = 0; db < 2; db++)
                #pragma unroll
                for (int j = 0; j < 4; j++) {
                    union { short4v v; short e[4]; } g;
                    #pragma unroll
                    for (int m = 0; m < 4; m++)
                        g.e[m] = f2bf(accO[db][j * 4 + m] * rl);
                    int dcol = db * 32 + j * 8 + 4 * hi;   // d = dcol + m
                    *reinterpret_cast<short4v*>(&pool[qrow * 68 + dcol]) = g.v;
                }
        }
        __syncthreads();

        {   // all 512 threads: 64 rows x 8 chunks x 16 B
            int r = t >> 3, c8 = t & 7;
            size_t gb = (size_t)(tile * 128 + u * 64 + r) * DM + head * 64 + c8 * 8;
            union { short8 v8; short4v h[2]; } u8;
            u8.h[0] = *reinterpret_cast<const short4v*>(&pool[r * 68 + c8 * 8]);
            u8.h[1] = *reinterpret_cast<const short4v*>(&pool[r * 68 + c8 * 8 + 4]);
            *reinterpret_cast<short8*>(&o_ws[gb]) = u8.v8;
        }
    }
}

// ---------------------------------------------------------------------------
// Kernel 3: O @ Wo^T -> fp32 out. 128x64 tiles, grid (32,16) = 512 blocks
// = 2 blocks/CU = 2 waves/SIMD (latency hiding). Wave = 64x32 out.
// ---------------------------------------------------------------------------
__global__ __launch_bounds__(256) void oproj_kernel(
    const __hip_bfloat16* __restrict__ o_in,
    const float* __restrict__ Wo,
    float* __restrict__ out)
{
    __shared__ __align__(16) char smem[24576];   // K-loop: As 16K + Bs 8K; epi: 64x68 fp32 (17.4K)
    short* As = (short*)smem;                    // 128 x 64
    short* Bs = As + 8192;                       // 64 x 64
    float* fpool = (float*)smem;

    const int m0 = blockIdx.x * 128;
    const int n0 = blockIdx.y * 64;

    const int t = threadIdx.x;
    const int lane = t & 63;
    const int w = t >> 6;
    const int quad = lane >> 4;
    const int ln = lane & 15;
    const int wm = (w >> 1) * 64;
    const int wn = (w & 1) * 32;

    floatx4 acc[4][2];
    #pragma unroll
    for (int i = 0; i < 4; i++)
        #pragma unroll
        for (int j = 0; j < 2; j++) acc[i][j] = (floatx4){0.f, 0.f, 0.f, 0.f};

    for (int k0 = 0; k0 < DM; k0 += 64) {
        #pragma unroll
        for (int it = 0; it < 4; it++) {
            int row = w * 32 + it * 8 + (lane >> 3);
            int sg = (lane & 7) ^ (row & 7);
            gl2lds16(&o_in[(size_t)(m0 + row) * DM + k0 + sg * 8], &As[(w * 32 + it * 8) * 64]);
        }
        #pragma unroll
        for (int p = 0; p < 2; p++) {
            int r = (t >> 3) + p * 32;
            int sg2 = t & 7;
            *reinterpret_cast<short8*>(&Bs[r * 64 + ((sg2 ^ (r & 7)) << 3)]) =
                load8_f32_as_bf16(&Wo[(size_t)(n0 + r) * DM + k0 + sg2 * 8]);
        }
        __syncthreads();

        short8 af[4][2], bfr[2][2];
        #pragma unroll
        for (int i = 0; i < 4; i++)
            #pragma unroll
            for (int kc = 0; kc < 2; kc++)
                af[i][kc] = *reinterpret_cast<const short8*>(
                    &As[(wm + i * 16 + ln) * 64 + (((kc * 4 + quad) ^ (ln & 7)) << 3)]);
        #pragma unroll
        for (int j = 0; j < 2; j++)
            #pragma unroll
            for (int kc = 0; kc < 2; kc++)
                bfr[j][kc] = *reinterpret_cast<const short8*>(
                    &Bs[(wn + j * 16 + ln) * 64 + (((kc * 4 + quad) ^ (ln & 7)) << 3)]);

        #pragma unroll
        for (int kc = 0; kc < 2; kc++)
            #pragma unroll
            for (int i = 0; i < 4; i++)
                #pragma unroll
                for (int j = 0; j < 2; j++)
                    acc[i][j] = __builtin_amdgcn_mfma_f32_16x16x32_bf16(
                        af[i][kc], bfr[j][kc], acc[i][j], 0, 0, 0);
        __syncthreads();
    }

    // Epilogue: two 64-row passes through fpool (pitch 68), coalesced stores.
    #pragma unroll
    for (int ph = 0; ph < 2; ph++) {
        if ((w >> 1) == ph) {
            #pragma unroll
            for (int j = 0; j < 2; j++)
                #pragma unroll
                for (int i = 0; i < 4; i++) {
                    int rl = i * 16 + quad * 4;
                    #pragma unroll
                    for (int r = 0; r < 4; r++)
                        fpool[(rl + r) * 68 + wn + j * 16 + ln] = acc[i][j][r];
                }
        }
        __syncthreads();
        int row = t >> 2;                        // 0..63
        int c0 = (t & 3) * 16;                   // 16 floats = 64 B per thread
        size_t gbase = (size_t)(m0 + ph * 64 + row) * DM + n0 + c0;
        #pragma unroll
        for (int c = 0; c < 4; c++)
            *reinterpret_cast<float4*>(&out[gbase + c * 4]) =
                *reinterpret_cast<const float4*>(&fpool[row * 68 + c0 + c * 4]);
        __syncthreads();
    }
}

extern "C" void kernel_launch(void* const* d_in, const int* in_sizes, int n_in,
                              void* d_out, int out_size, void* d_ws, size_t ws_size,
                              hipStream_t stream) {
    const float* x  = (const float*)d_in[0];
    const int* tp   = (const int*)d_in[1];
    const float* Wq = (const float*)d_in[2];
    const float* Wk = (const float*)d_in[3];
    const float* Wv = (const float*)d_in[4];
    const float* Wo = (const float*)d_in[5];
    float* out = (float*)d_out;

    char* ws = (char*)d_ws;
    const size_t MB = 1024 * 1024;
    __hip_bfloat16* xb    = (__hip_bfloat16*)(ws);              // 8 MB; reused as o_ws
    __hip_bfloat16* q_ws  = (__hip_bfloat16*)(ws + 8  * MB);    // [SEQ][DM]
    __hip_bfloat16* k_ws  = (__hip_bfloat16*)(ws + 16 * MB);    // [SEQ][DM]
    __hip_bfloat16* vt_ws = (__hip_bfloat16*)(ws + 24 * MB);    // [1024][SEQ]
    __hip_bfloat16* o_ws  = xb;
    __hip_bfloat16* Wqb = (__hip_bfloat16*)d_out;                // parked in d_out
    __hip_bfloat16* Wkb = Wqb + (size_t)DM * DM;
    __hip_bfloat16* Wvb = Wkb + (size_t)DM * DM;
    float2* tab = (float2*)((char*)d_out + 6 * MB);

    prep_kernel<<<4096, 256, 0, stream>>>(x, Wq, Wk, Wv, tp, xb, Wqb, Wkb, Wvb, tab);
    qkv_rope_kernel<<<dim3(32, 24), 256, 0, stream>>>(xb, tab, Wqb, Wkb, Wvb, q_ws, k_ws, vt_ws);
    attn_kernel<<<512, 512, 0, stream>>>(q_ws, k_ws, vt_ws, o_ws);
    oproj_kernel<<<dim3(32, 16), 256, 0, stream>>>(o_ws, Wo, out);
}

// Round 13
// 202.997 us; speedup vs baseline: 1.1025x; 1.1025x over previous
//
#include <hip/hip_runtime.h>
#include <hip/hip_bf16.h>
#include <math.h>

// CausalMHA+RoPE: B=1, S=4096, DM=1024, H=16, DK=64. fp32 in / fp32 out.
// R24: restore R19 (verified session best: attn 56.3us, total 204.97us,
//      clean counters) with ONE change: all s_setprio removed from attn.
//      Mechanism: R19 is a barrier-locked lockstep regime (all 16 waves in
//      the single block at the same phase) -- m190 measured setprio
//      NEGATIVE there (it only pays on role-split schedules, m218b).
//      R20-R23 post-mortems: every pipelining attempt (reg-carried P,
//      LDS-carried P, launch-bounds floor, 2-block split) lost to R19 via
//      spill or failed co-residency; R19 is the structure optimum for this
//      session. prep/qkv/oproj unchanged (verified R7+).

#define SEQ 4096
#define DM  1024
#define NH  16
#define DK  64

typedef __attribute__((ext_vector_type(8))) short short8;    // 8 bf16 (MFMA A/B frag)
typedef __attribute__((ext_vector_type(4))) float floatx4;   // 16x16 C/D frag
typedef __attribute__((ext_vector_type(16))) float floatx16; // 32x32 C/D frag
typedef __attribute__((ext_vector_type(4))) short short4v;   // 4 bf16 (8 B)

static __device__ __forceinline__ short f2bf(float f) {
    __hip_bfloat16 h = __float2bfloat16(f);
    return __builtin_bit_cast(short, h);
}

static __device__ __forceinline__ float fast_exp2(float x) {
#if __has_builtin(__builtin_amdgcn_exp2f)
    return __builtin_amdgcn_exp2f(x);
#else
    return exp2f(x);
#endif
}

static __device__ __forceinline__ short8 load8_f32_as_bf16(const float* p) {
    float4 a = *reinterpret_cast<const float4*>(p);
    float4 b = *reinterpret_cast<const float4*>(p + 4);
    short8 s;
    s[0] = f2bf(a.x); s[1] = f2bf(a.y); s[2] = f2bf(a.z); s[3] = f2bf(a.w);
    s[4] = f2bf(b.x); s[5] = f2bf(b.y); s[6] = f2bf(b.z); s[7] = f2bf(b.w);
    return s;
}

// async global->LDS, 16 B/lane. LDS dest = wave-uniform base + lane*16.
static __device__ __forceinline__ void gl2lds16(const __hip_bfloat16* g, short* l) {
    __builtin_amdgcn_global_load_lds(
        (const __attribute__((address_space(1))) unsigned int*)g,
        (__attribute__((address_space(3))) unsigned int*)l, 16, 0, 0);
}

static __device__ __forceinline__ int read_pos(const int* tp32, int s) {
    return (tp32[1] == 1) ? tp32[s] : tp32[2 * s];
}

// ---------------------------------------------------------------------------
// Fused prep: fp32->bf16 for x/Wq/Wk/Wv + RoPE cos/sin table. Grid 4096.
// ---------------------------------------------------------------------------
__global__ __launch_bounds__(256) void prep_kernel(
    const float* __restrict__ x,  const float* __restrict__ Wq,
    const float* __restrict__ Wk, const float* __restrict__ Wv,
    const int* __restrict__ tp,
    __hip_bfloat16* __restrict__ xb,  __hip_bfloat16* __restrict__ Wqb,
    __hip_bfloat16* __restrict__ Wkb, __hip_bfloat16* __restrict__ Wvb,
    float2* __restrict__ tab)
{
    int b = blockIdx.x;
    if (b < 3584) {
        const float* src; __hip_bfloat16* dst; int off;
        if (b < 2048)      { src = x;  dst = xb;  off = b; }
        else if (b < 2560) { src = Wq; dst = Wqb; off = b - 2048; }
        else if (b < 3072) { src = Wk; dst = Wkb; off = b - 2560; }
        else               { src = Wv; dst = Wvb; off = b - 3072; }
        size_t i = (size_t)off * 256 + threadIdx.x;
        short8 v = load8_f32_as_bf16(src + i * 8);
        *reinterpret_cast<short8*>((short*)dst + i * 8) = v;
    } else {
        int idx = (b - 3584) * 256 + threadIdx.x;   // SEQ*32 entries
        if (idx < SEQ * 32) {
            int s = idx >> 5, pair = idx & 31;
            float inv_freq = exp2f(-(float)(2 * pair) * (13.287712379549449f / 64.f));
            float sn, cs;
            sincosf((float)read_pos(tp, s) * inv_freq, &sn, &cs);
            tab[idx] = make_float2(cs, sn);
        }
    }
}

// ---------------------------------------------------------------------------
// Kernel 1: QKV NT-GEMM + RoPE epilogue. qscale folds log2(e) so attn uses
// native exp2 (v_exp_f32) directly.
// ---------------------------------------------------------------------------
__global__ __launch_bounds__(256) void qkv_rope_kernel(
    const __hip_bfloat16* __restrict__ xb,
    const float2* __restrict__ tab,
    const __hip_bfloat16* __restrict__ Wqb,
    const __hip_bfloat16* __restrict__ Wkb,
    const __hip_bfloat16* __restrict__ Wvb,
    __hip_bfloat16* __restrict__ q_ws,
    __hip_bfloat16* __restrict__ k_ws,
    __hip_bfloat16* __restrict__ vt_ws)
{
    __shared__ __align__(16) short pool[17408];
    short* As = pool;
    short* Bs = pool + 8192;

    const int by = blockIdx.y;
    const int wsel = by >> 3;
    const __hip_bfloat16* W = (wsel == 0) ? Wqb : (wsel == 1 ? Wkb : Wvb);
    const int nloc0 = (by & 7) * 128;
    const int m0 = blockIdx.x * 128;

    const int t = threadIdx.x;
    const int lane = t & 63;
    const int w = t >> 6;
    const int quad = lane >> 4;
    const int ln = lane & 15;
    const int wm = (w >> 1) * 64;
    const int wn = (w & 1) * 64;

    floatx4 acc[4][4];
    #pragma unroll
    for (int i = 0; i < 4; i++)
        #pragma unroll
        for (int j = 0; j < 4; j++) acc[i][j] = (floatx4){0.f, 0.f, 0.f, 0.f};

    for (int k0 = 0; k0 < DM; k0 += 64) {
        #pragma unroll
        for (int it = 0; it < 4; it++) {
            int row = w * 32 + it * 8 + (lane >> 3);
            int sg = (lane & 7) ^ (row & 7);
            gl2lds16(&xb[(size_t)(m0 + row) * DM + k0 + sg * 8], &As[(w * 32 + it * 8) * 64]);
            gl2lds16(&W[(size_t)(nloc0 + row) * DM + k0 + sg * 8], &Bs[(w * 32 + it * 8) * 64]);
        }
        __syncthreads();

        short8 af[4][2], bfr[4][2];
        #pragma unroll
        for (int i = 0; i < 4; i++)
            #pragma unroll
            for (int kc = 0; kc < 2; kc++)
                af[i][kc] = *reinterpret_cast<const short8*>(
                    &As[(wm + i * 16 + ln) * 64 + (((kc * 4 + quad) ^ (ln & 7)) << 3)]);
        #pragma unroll
        for (int j = 0; j < 4; j++)
            #pragma unroll
            for (int kc = 0; kc < 2; kc++)
                bfr[j][kc] = *reinterpret_cast<const short8*>(
                    &Bs[(wn + j * 16 + ln) * 64 + (((kc * 4 + quad) ^ (ln & 7)) << 3)]);

        #pragma unroll
        for (int kc = 0; kc < 2; kc++)
            #pragma unroll
            for (int i = 0; i < 4; i++)
                #pragma unroll
                for (int j = 0; j < 4; j++)
                    acc[i][j] = __builtin_amdgcn_mfma_f32_16x16x32_bf16(
                        af[i][kc], bfr[j][kc], acc[i][j], 0, 0, 0);
        __syncthreads();
    }

    if (wsel < 2) {
        __hip_bfloat16* dst = (wsel == 0) ? q_ws : k_ws;
        // q scale = (1/sqrt(dk)) * log2(e) so attn softmax uses exp2 natively.
        const float qscale = (wsel == 0) ? 0.18033688011112042f : 1.0f;
        #pragma unroll
        for (int j = 0; j < 4; j++) {
            int cnl = wn + j * 16 + ln;
            int pair = ((nloc0 + cnl) & 63) >> 1;
            #pragma unroll
            for (int i = 0; i < 4; i++) {
                int rowl = wm + i * 16 + quad * 4;
                #pragma unroll
                for (int r = 0; r < 4; r++) {
                    float2 t2 = tab[(size_t)(m0 + rowl + r) * 32 + pair];
                    float val = acc[i][j][r];
                    float partner = __shfl_xor(val, 1, 64);
                    float res = val * t2.x + (((lane & 1) ? partner : -partner) * t2.y);
                    pool[(rowl + r) * 136 + cnl] = f2bf(res * qscale);
                }
            }
        }
        __syncthreads();
        int row = t >> 1, half = t & 1;
        size_t gbase = (size_t)(m0 + row) * DM + nloc0 + half * 64;
        #pragma unroll
        for (int c = 0; c < 8; c++)
            *reinterpret_cast<short8*>(&dst[gbase + c * 8]) =
                *reinterpret_cast<const short8*>(&pool[row * 136 + half * 64 + c * 8]);
    } else {
        #pragma unroll
        for (int j = 0; j < 4; j++) {
            int cnl = wn + j * 16 + ln;
            #pragma unroll
            for (int i = 0; i < 4; i++) {
                int s0 = wm + i * 16 + quad * 4;
                #pragma unroll
                for (int r = 0; r < 4; r++)
                    pool[cnl * 136 + s0 + r] = f2bf(acc[i][j][r]);
            }
        }
        __syncthreads();
        int cnl = t >> 1, sh = t & 1;
        size_t base = (size_t)(nloc0 + cnl) * SEQ + m0 + sh * 64;
        #pragma unroll
        for (int c = 0; c < 8; c++)
            *reinterpret_cast<short8*>(&vt_ws[base + c * 8]) =
                *reinterpret_cast<const short8*>(&pool[cnl * 136 + sh * 64 + c * 8]);
    }
}

// ---------------------------------------------------------------------------
// Kernel 2: causal flash attention, 32x32 MFMA, in-register softmax (R15
// math, verified). R19 structure: 1024 thr = 16 waves = 4 q-groups (ww) x
// 4 key quarters (kq); each wave does ONE kb32 = kq per 128-key step.
// 4-way accO/l merge per pass via SoA LDS scratch. Uniform 33-step pairing
// (A=31-jp then B=jp). Grid 256 = 1 block/CU, 16 waves/CU (4/SIMD).
// R24: s_setprio removed (lockstep regime -- m190: negative there).
//
// Layouts (32x32x16 bf16):
//   A-frag: row = lane&31, k = (lane>>5)*8 + e
//   B-frag: col = lane&31, k = (lane>>5)*8 + e
//   C/D   : col = lane&31, row = (reg&3) + 8*(reg>>2) + 4*(lane>>5)
// K LDS rows permuted by swap(bit2,bit3) so S^T output regs are already in
// PV B-frag key order.
// ---------------------------------------------------------------------------
__global__ __launch_bounds__(1024, 1) void attn_kernel(
    const __hip_bfloat16* __restrict__ q_ws,
    const __hip_bfloat16* __restrict__ k_ws,
    const __hip_bfloat16* __restrict__ vt_ws,
    __hip_bfloat16* __restrict__ o_ws)   // [SEQ][DM]
{
    __shared__ __align__(16) short Kt[2][128 * 64];   // [buf][key_row][dk]  32 KB
    __shared__ __align__(16) short Vt[2][64 * 128];   // [buf][d][key]       32 KB

    const int bid = (int)blockIdx.x;
    const int head = bid & 15;            // 2 heads per XCD (bid%8 = XCD)
    const int jp = bid >> 4;              // 0..15 pair index

    const int t = threadIdx.x;
    const int lane = t & 63;
    const int w = t >> 6;                 // 0..15
    const int ww = w & 3;                 // q-row group within tile
    const int kq = w >> 2;                // key quarter = kb32
    const int hi = lane >> 5;             // k-half select
    const int l31 = lane & 31;

    auto stage = [&](int b, int kb) {     // stage keys [kb, kb+128), 16 waves
        {   // K: 8 rows per wave
            int r = w * 8 + (lane >> 3);
            int keyloc = (r & ~12) | ((r & 4) << 1) | ((r & 8) >> 1);  // swap b2<->b3
            int g = (lane & 7) ^ (r & 7);
            gl2lds16(&k_ws[(size_t)(kb + keyloc) * DM + head * 64 + g * 8],
                     &Kt[b][(w * 8) * 64]);
        }
        {   // V^T: 4 d-rows per wave
            int d = w * 4 + (lane >> 4);
            int g = (lane & 15) ^ (d & 7);
            gl2lds16(&vt_ws[(size_t)(head * 64 + d) * SEQ + kb + g * 8],
                     &Vt[b][(w * 4) * 128]);
        }
    };

    #pragma unroll 1
    for (int pass = 0; pass < 2; pass++) {
        const int tile = pass ? jp : (31 - jp);
        const int nstep = tile + 1;                // 128-key steps
        const int q0 = tile * 128 + ww * 32;       // q-group's first row

        // Q fragments (B operand), k-chunk c: k = c*16 + hi*8 + 0..7
        short8 qf[4];
        #pragma unroll
        for (int c = 0; c < 4; c++)
            qf[c] = *reinterpret_cast<const short8*>(
                &q_ws[(size_t)(q0 + l31) * DM + head * 64 + c * 16 + hi * 8]);

        floatx16 accO[2];
        #pragma unroll
        for (int db = 0; db < 2; db++)
            #pragma unroll
            for (int i = 0; i < 16; i++) accO[db][i] = 0.f;
        float l = 0.f;

        __syncthreads();                  // prior pass LDS reads done
        stage(0, 0);
        int buf = 0;
        for (int st = 0; st < nstep; st++) {
            __syncthreads();
            if (st + 1 < nstep) stage(buf ^ 1, (st + 1) * 128);
            const bool last = (st == nstep - 1);

            if (!(last && kq > ww)) {             // wave-uniform skip above diagonal
                const int kb32 = kq;
                const int krow = kb32 * 32 + l31; // Kt physical row
                short8 kfr[4];
                #pragma unroll
                for (int kc = 0; kc < 4; kc++) {
                    int g = (kc * 2 + hi) ^ (krow & 7);
                    kfr[kc] = *reinterpret_cast<const short8*>(&Kt[buf][krow * 64 + g * 8]);
                }
                floatx16 s;
                #pragma unroll
                for (int i = 0; i < 16; i++) s[i] = 0.f;
                #pragma unroll
                for (int kc = 0; kc < 4; kc++)
                    s = __builtin_amdgcn_mfma_f32_32x32x16_bf16(kfr[kc], qf[kc], s, 0, 0, 0);

                if (last) {                       // diagonal mask (key = swapped row)
                    #pragma unroll
                    for (int r = 0; r < 16; r++) {
                        int key_l = kb32 * 32 + (r & 7) + 2 * (r & 8) + 8 * hi;
                        if (key_l > ww * 32 + l31) s[r] = -1e9f;
                    }
                }
                float p[16];
                #pragma unroll
                for (int r = 0; r < 16; r++) { p[r] = fast_exp2(s[r]); l += p[r]; }

                // P B-frags in key-natural order: chunk c -> keys c*16+hi*8+e
                union { short8 v; short e[8]; } pb[2];
                #pragma unroll
                for (int c = 0; c < 2; c++)
                    #pragma unroll
                    for (int e8 = 0; e8 < 8; e8++)
                        pb[c].e[e8] = f2bf(p[c * 8 + e8]);

                #pragma unroll
                for (int db = 0; db < 2; db++) {
                    const int vrow = db * 32 + l31;
                    short8 vfr[2];
                    #pragma unroll
                    for (int c = 0; c < 2; c++) {
                        int g = (kb32 * 4 + c * 2 + hi) ^ (vrow & 7);
                        vfr[c] = *reinterpret_cast<const short8*>(&Vt[buf][vrow * 128 + g * 8]);
                    }
                    accO[db] = __builtin_amdgcn_mfma_f32_32x32x16_bf16(vfr[0], pb[0].v, accO[db], 0, 0, 0);
                    accO[db] = __builtin_amdgcn_mfma_f32_32x32x16_bf16(vfr[1], pb[1].v, accO[db], 0, 0, 0);
                }
            }
            buf ^= 1;
        }

        // ---- 4-way merge over key quarters (accO, l additive over keys) ----
        // SoA scratch: Kt = 8192 f32 planes (lane stride 4B, conflict-free);
        // l values in Vt.
        float* scrK = (float*)Kt;
        float* scrV = (float*)Vt;
        __syncthreads();                  // all Kt/Vt compute reads done
        {   // Round 1a: kq{2,3} -> kq{0,1}: accO[0] + l
            const int slot = (ww * 2 + (kq & 1)) * 64 + lane;   // same for writer/reader pair
            if (kq >= 2) {
                #pragma unroll
                for (int i = 0; i < 16; i++) scrK[i * 512 + slot] = accO[0][i];
                scrV[slot] = l;
            }
            __syncthreads();
            if (kq < 2) {
                #pragma unroll
                for (int i = 0; i < 16; i++) accO[0][i] += scrK[i * 512 + slot];
                l += scrV[slot];
            }
            __syncthreads();
            // Round 1b: accO[1]
            if (kq >= 2) {
                #pragma unroll
                for (int i = 0; i < 16; i++) scrK[i * 512 + slot] = accO[1][i];
            }
            __syncthreads();
            if (kq < 2) {
                #pragma unroll
                for (int i = 0; i < 16; i++) accO[1][i] += scrK[i * 512 + slot];
            }
            __syncthreads();
            // Round 2: kq1 -> kq0: accO[0..1] + l
            const int slot2 = ww * 64 + lane;
            if (kq == 1) {
                #pragma unroll
                for (int i = 0; i < 16; i++) scrK[i * 256 + slot2] = accO[0][i];
                #pragma unroll
                for (int i = 0; i < 16; i++) scrK[(16 + i) * 256 + slot2] = accO[1][i];
                scrV[slot2] = l;
            }
            __syncthreads();
            if (kq == 0) {
                #pragma unroll
                for (int i = 0; i < 16; i++) accO[0][i] += scrK[i * 256 + slot2];
                #pragma unroll
                for (int i = 0; i < 16; i++) accO[1][i] += scrK[(16 + i) * 256 + slot2];
                l += scrV[slot2];
            }
        }

        // Epilogue (kq=0 waves hold full sums): l fold, scale, pool, stores.
        float lf = l + __shfl_xor(l, 32, 64);
        float rl = 1.f / lf;

        __syncthreads();                  // round-2 scratch reads done
        short* pool = (short*)Kt;         // 128 x 68 bf16 = 17408 B
        if (kq == 0) {
            const int qrow = ww * 32 + l31;
            #pragma unroll
            for (int db = 0; db < 2; db++)
                #pragma unroll
                for (int j = 0; j < 4; j++) {
                    union { short4v v; short e[4]; } g;
                    #pragma unroll
                    for (int m = 0; m < 4; m++)
                        g.e[m] = f2bf(accO[db][j * 4 + m] * rl);
                    int dcol = db * 32 + j * 8 + 4 * hi;   // d = dcol + m
                    *reinterpret_cast<short4v*>(&pool[qrow * 68 + dcol]) = g.v;
                }
        }
        __syncthreads();

        {   // all 1024 threads: 128 rows x 8 chunks x 16 B
            int r = t >> 3, c8 = t & 7;
            size_t gb = (size_t)(tile * 128 + r) * DM + head * 64 + c8 * 8;
            union { short8 v8; short4v h[2]; } u;
            u.h[0] = *reinterpret_cast<const short4v*>(&pool[r * 68 + c8 * 8]);
            u.h[1] = *reinterpret_cast<const short4v*>(&pool[r * 68 + c8 * 8 + 4]);
            *reinterpret_cast<short8*>(&o_ws[gb]) = u.v8;
        }
    }
}

// ---------------------------------------------------------------------------
// Kernel 3: O @ Wo^T -> fp32 out. 128x64 tiles, grid (32,16) = 512 blocks
// = 2 blocks/CU = 2 waves/SIMD (latency hiding). Wave = 64x32 out.
// ---------------------------------------------------------------------------
__global__ __launch_bounds__(256) void oproj_kernel(
    const __hip_bfloat16* __restrict__ o_in,
    const float* __restrict__ Wo,
    float* __restrict__ out)
{
    __shared__ __align__(16) char smem[24576];   // K-loop: As 16K + Bs 8K; epi: 64x68 fp32 (17.4K)
    short* As = (short*)smem;                    // 128 x 64
    short* Bs = As + 8192;                       // 64 x 64
    float* fpool = (float*)smem;

    const int m0 = blockIdx.x * 128;
    const int n0 = blockIdx.y * 64;

    const int t = threadIdx.x;
    const int lane = t & 63;
    const int w = t >> 6;
    const int quad = lane >> 4;
    const int ln = lane & 15;
    const int wm = (w >> 1) * 64;
    const int wn = (w & 1) * 32;

    floatx4 acc[4][2];
    #pragma unroll
    for (int i = 0; i < 4; i++)
        #pragma unroll
        for (int j = 0; j < 2; j++) acc[i][j] = (floatx4){0.f, 0.f, 0.f, 0.f};

    for (int k0 = 0; k0 < DM; k0 += 64) {
        #pragma unroll
        for (int it = 0; it < 4; it++) {
            int row = w * 32 + it * 8 + (lane >> 3);
            int sg = (lane & 7) ^ (row & 7);
            gl2lds16(&o_in[(size_t)(m0 + row) * DM + k0 + sg * 8], &As[(w * 32 + it * 8) * 64]);
        }
        #pragma unroll
        for (int p = 0; p < 2; p++) {
            int r = (t >> 3) + p * 32;
            int sg2 = t & 7;
            *reinterpret_cast<short8*>(&Bs[r * 64 + ((sg2 ^ (r & 7)) << 3)]) =
                load8_f32_as_bf16(&Wo[(size_t)(n0 + r) * DM + k0 + sg2 * 8]);
        }
        __syncthreads();

        short8 af[4][2], bfr[2][2];
        #pragma unroll
        for (int i = 0; i < 4; i++)
            #pragma unroll
            for (int kc = 0; kc < 2; kc++)
                af[i][kc] = *reinterpret_cast<const short8*>(
                    &As[(wm + i * 16 + ln) * 64 + (((kc * 4 + quad) ^ (ln & 7)) << 3)]);
        #pragma unroll
        for (int j = 0; j < 2; j++)
            #pragma unroll
            for (int kc = 0; kc < 2; kc++)
                bfr[j][kc] = *reinterpret_cast<const short8*>(
                    &Bs[(wn + j * 16 + ln) * 64 + (((kc * 4 + quad) ^ (ln & 7)) << 3)]);

        #pragma unroll
        for (int kc = 0; kc < 2; kc++)
            #pragma unroll
            for (int i = 0; i < 4; i++)
                #pragma unroll
                for (int j = 0; j < 2; j++)
                    acc[i][j] = __builtin_amdgcn_mfma_f32_16x16x32_bf16(
                        af[i][kc], bfr[j][kc], acc[i][j], 0, 0, 0);
        __syncthreads();
    }

    // Epilogue: two 64-row passes through fpool (pitch 68), coalesced stores.
    #pragma unroll
    for (int ph = 0; ph < 2; ph++) {
        if ((w >> 1) == ph) {
            #pragma unroll
            for (int j = 0; j < 2; j++)
                #pragma unroll
                for (int i = 0; i < 4; i++) {
                    int rl = i * 16 + quad * 4;
                    #pragma unroll
                    for (int r = 0; r < 4; r++)
                        fpool[(rl + r) * 68 + wn + j * 16 + ln] = acc[i][j][r];
                }
        }
        __syncthreads();
        int row = t >> 2;                        // 0..63
        int c0 = (t & 3) * 16;                   // 16 floats = 64 B per thread
        size_t gbase = (size_t)(m0 + ph * 64 + row) * DM + n0 + c0;
        #pragma unroll
        for (int c = 0; c < 4; c++)
            *reinterpret_cast<float4*>(&out[gbase + c * 4]) =
                *reinterpret_cast<const float4*>(&fpool[row * 68 + c0 + c * 4]);
        __syncthreads();
    }
}

extern "C" void kernel_launch(void* const* d_in, const int* in_sizes, int n_in,
                              void* d_out, int out_size, void* d_ws, size_t ws_size,
                              hipStream_t stream) {
    const float* x  = (const float*)d_in[0];
    const int* tp   = (const int*)d_in[1];
    const float* Wq = (const float*)d_in[2];
    const float* Wk = (const float*)d_in[3];
    const float* Wv = (const float*)d_in[4];
    const float* Wo = (const float*)d_in[5];
    float* out = (float*)d_out;

    char* ws = (char*)d_ws;
    const size_t MB = 1024 * 1024;
    __hip_bfloat16* xb    = (__hip_bfloat16*)(ws);              // 8 MB; reused as o_ws
    __hip_bfloat16* q_ws  = (__hip_bfloat16*)(ws + 8  * MB);    // [SEQ][DM]
    __hip_bfloat16* k_ws  = (__hip_bfloat16*)(ws + 16 * MB);    // [SEQ][DM]
    __hip_bfloat16* vt_ws = (__hip_bfloat16*)(ws + 24 * MB);    // [1024][SEQ]
    __hip_bfloat16* o_ws  = xb;
    __hip_bfloat16* Wqb = (__hip_bfloat16*)d_out;                // parked in d_out
    __hip_bfloat16* Wkb = Wqb + (size_t)DM * DM;
    __hip_bfloat16* Wvb = Wkb + (size_t)DM * DM;
    float2* tab = (float2*)((char*)d_out + 6 * MB);

    prep_kernel<<<4096, 256, 0, stream>>>(x, Wq, Wk, Wv, tp, xb, Wqb, Wkb, Wvb, tab);
    qkv_rope_kernel<<<dim3(32, 24), 256, 0, stream>>>(xb, tab, Wqb, Wkb, Wvb, q_ws, k_ws, vt_ws);
    attn_kernel<<<256, 1024, 0, stream>>>(q_ws, k_ws, vt_ws, o_ws);
    oproj_kernel<<<dim3(32, 16), 256, 0, stream>>>(o_ws, Wo, out);
}